// Round 8
// baseline (697.009 us; speedup 1.0000x reference)
//
#include <hip/hip_runtime.h>
#include <hip/hip_bf16.h>
#include <hip/hip_cooperative_groups.h>

namespace cg = cooperative_groups;

#define N_NODES 100000
#define N_EDGES 600000
#define N_LABELS 200000
#define DIM 128
#define NPARTS 391           // ceil(N_NODES/256)
#define NT_TILES 6250        // N_NODES / 16 exactly
#define GRID 512             // coop grid: 2 blocks/CU, well under the 3/CU capacity from launch_bounds
#define NTHREADS (GRID * 256)
#define GEMM_GRID 512        // fallback gemm grid

using short8 = __attribute__((ext_vector_type(8))) short;
using f32x2  = __attribute__((ext_vector_type(2))) float;
using f32x4  = __attribute__((ext_vector_type(4))) float;
using u32x2  = __attribute__((ext_vector_type(2))) unsigned;
using u32x4  = __attribute__((ext_vector_type(4))) unsigned;

__device__ __forceinline__ float b2f(short s) {
    union { unsigned u; float f; } c;
    c.u = ((unsigned)(unsigned short)s) << 16;
    return c.f;
}
__device__ __forceinline__ f32x2 b2f2(unsigned u) {
    union { unsigned u; float f; } lo, hi;
    lo.u = u << 16;
    hi.u = u & 0xffff0000u;
    f32x2 r; r[0] = lo.f; r[1] = hi.f;
    return r;
}
__device__ __forceinline__ short f2b(float f) {
    __hip_bfloat16 h = __float2bfloat16(f);
    return *reinterpret_cast<short*>(&h);
}
__device__ __forceinline__ unsigned f2b2u(float x, float y) {
    __hip_bfloat162 h = __float22bfloat162_rn(make_float2(x, y));
    return *reinterpret_cast<unsigned*>(&h);
}

struct Params {
    const int* ei; const int* eli; const float* emb;
    const float* W1l; const float* b1; const float* W1r;
    const float* W2l; const float* b2; const float* W2r;
    const float* Wlin; const float* blin;
    short* BT1;
    float* up; float* uq; float* vp; float* vq; float2* cpq;
    int* cnt; int* rowptr; int* widx; int* adj; int* partials;
    short* Hl; short* Hr;
    float2* S; float2* T; float* p; float* q; float* out;
};

// ================= cooperative mega-kernel =================
__global__ __launch_bounds__(256, 3) void mega_k(Params P) {
    cg::grid_group grid = cg::this_grid();
    __shared__ int sbuf[512];

    const int bid  = blockIdx.x;
    const int tid  = threadIdx.x;
    const int gtid = bid * 256 + tid;
    const int lane = tid & 63;
    const int wave = tid >> 6;
    const int quad = lane >> 4;
    const int l16  = lane & 15;

    // ---------- phase 0: zero cnt + prep BT1 / projections / cpq ----------
    for (int i = gtid; i < N_NODES; i += NTHREADS) P.cnt[i] = 0;
    if (bid < 128) {
        int i = bid * 256 + tid;
        int n = i >> 7, k = i & 127;
        float v = (n < 128) ? P.W1l[k * 128 + n] : P.W1r[k * 128 + (n - 128)];
        P.BT1[n * 128 + k] = f2b(v);
    } else if (bid == 128) {
        const float* W = (tid < 128) ? P.W2l : P.W2r;
        int k = tid & 127;
        float s0 = 0.f, s1 = 0.f;
        for (int n = 0; n < 128; ++n) {
            float w = W[k * 128 + n];
            s0 += w * P.Wlin[n];
            s1 += w * P.Wlin[128 + n];
        }
        if (tid < 128) { P.up[k] = s0; P.uq[k] = s1; }
        else           { P.vp[k] = s0; P.vq[k] = s1; }
    } else if (bid == 129) {
        if (tid < 64) {
            float p0 = P.b2[tid] * P.Wlin[tid] + P.b2[tid + 64] * P.Wlin[tid + 64];
            float q0 = P.b2[tid] * P.Wlin[128 + tid] + P.b2[tid + 64] * P.Wlin[192 + tid];
#pragma unroll
            for (int m = 1; m <= 32; m <<= 1) {
                p0 += __shfl_xor(p0, m, 64);
                q0 += __shfl_xor(q0, m, 64);
            }
            if (tid == 0) *P.cpq = make_float2(p0, q0);
        }
    }
    grid.sync();

    // ---------- phase 1: count degrees ----------
    for (int e = gtid; e < N_EDGES; e += NTHREADS) atomicAdd(&P.cnt[P.ei[N_EDGES + e]], 1);
    grid.sync();

    // ---------- phase 2: per-chunk exclusive scan ----------
    if (bid < NPARTS) {
        int i = bid * 256 + tid;
        int v = (i < N_NODES) ? P.cnt[i] : 0;
        sbuf[tid] = v;
        __syncthreads();
        for (int off = 1; off < 256; off <<= 1) {
            int x = sbuf[tid];
            int y = (tid >= off) ? sbuf[tid - off] : 0;
            __syncthreads();
            sbuf[tid] = x + y;
            __syncthreads();
        }
        if (i < N_NODES) P.rowptr[i] = sbuf[tid] - v;
        if (tid == 255) P.partials[bid] = sbuf[255];
    }
    grid.sync();

    // ---------- phase 3: apply chunk base ----------
    if (bid < NPARTS) {
        int s = 0;
        for (int t2 = tid; t2 < bid; t2 += 256) s += P.partials[t2];
#pragma unroll
        for (int m = 1; m <= 32; m <<= 1) s += __shfl_xor(s, m, 64);
        if (lane == 0) sbuf[wave] = s;
        __syncthreads();
        int base = sbuf[0] + sbuf[1] + sbuf[2] + sbuf[3];
        int i = bid * 256 + tid;
        if (i < N_NODES) {
            int r = P.rowptr[i] + base;
            P.rowptr[i] = r;
            P.widx[i] = r;
        }
        if (bid == NPARTS - 1 && tid == 0) P.rowptr[N_NODES] = base + P.partials[NPARTS - 1];
    }
    grid.sync();

    // ---------- phase 4: fill adjacency (blocks 0..127)  ||  GEMM1 (blocks 128..511) ----------
    if (bid < 128) {
        for (int e = bid * 256 + tid; e < N_EDGES; e += 128 * 256) {
            int d = P.ei[N_EDGES + e];
            int pos = atomicAdd(&P.widx[d], 1);
            P.adj[pos] = P.ei[e];
        }
    } else {
        int gb = bid - 128;                          // 0..383
        short* __restrict__ H = (wave < 2) ? P.Hl : P.Hr;
        int fbase = (wave & 1) * 64;

        short8 Wf[4][4];
#pragma unroll
        for (int t = 0; t < 4; ++t)
#pragma unroll
            for (int kk = 0; kk < 4; ++kk)
                Wf[t][kk] = *(const short8*)(P.BT1 + (wave * 64 + t * 16 + l16) * DIM + kk * 32 + quad * 8);

        for (int s = gb; s < NT_TILES; s += 384) {
            long arow = (long)s * 16 + l16;
            short8 xf[4];
#pragma unroll
            for (int kk = 0; kk < 4; ++kk) {
                f32x4 a0 = *(const f32x4*)(P.emb + arow * DIM + kk * 32 + quad * 8);
                f32x4 a1 = *(const f32x4*)(P.emb + arow * DIM + kk * 32 + quad * 8 + 4);
                unsigned* xu = (unsigned*)&xf[kk];
                xu[0] = f2b2u(a0[0], a0[1]);
                xu[1] = f2b2u(a0[2], a0[3]);
                xu[2] = f2b2u(a1[0], a1[1]);
                xu[3] = f2b2u(a1[2], a1[3]);
            }
            f32x4 acc[4];
#pragma unroll
            for (int t = 0; t < 4; ++t)
#pragma unroll
                for (int r = 0; r < 4; ++r) acc[t][r] = 0.f;
#pragma unroll
            for (int kk = 0; kk < 4; ++kk)
#pragma unroll
                for (int t = 0; t < 4; ++t)
                    acc[t] = __builtin_amdgcn_mfma_f32_16x16x32_bf16(Wf[t][kk], xf[kk], acc[t], 0, 0, 0);
#pragma unroll
            for (int t = 0; t < 4; ++t) {
                u32x2 o;
                o[0] = f2b2u(acc[t][0], acc[t][1]);
                o[1] = f2b2u(acc[t][2], acc[t][3]);
                *(u32x2*)(H + arow * DIM + fbase + t * 16 + quad * 4) = o;
            }
        }
    }
    grid.sync();

    // ---------- phase 5: agg1 — 4 nodes per wave, 16-lane group per node ----------
    {
        int wgid = bid * 4 + wave;
        int f0 = l16 << 3;
        for (int qi = wgid; qi < N_NODES / 4; qi += GRID * 4) {
            int node = qi * 4 + quad;
            int beg = P.rowptr[node], end = P.rowptr[node + 1];
            f32x2 sum[4];
#pragma unroll
            for (int d = 0; d < 4; ++d) { sum[d][0] = 0.f; sum[d][1] = 0.f; }

            int e = beg;
            u32x4 h0;
            if (e < end) h0 = *(const u32x4*)(P.Hl + (long)P.adj[e] * DIM + f0);
            for (; e < end;) {
                int e1 = e + 1;
                u32x4 h1;
                if (e1 < end) h1 = *(const u32x4*)(P.Hl + (long)P.adj[e1] * DIM + f0);
#pragma unroll
                for (int d = 0; d < 4; ++d) sum[d] += b2f2(h0[d]);
                h0 = h1;
                e = e1;
            }

            int deg = end - beg;
            float inv = deg > 0 ? 1.f / (float)deg : 0.f;
            f32x4 bb0 = *(const f32x4*)(P.b1 + f0);
            f32x4 bb1 = *(const f32x4*)(P.b1 + f0 + 4);
            u32x4 hru = *(const u32x4*)(P.Hr + (long)node * DIM + f0);
            float x[8];
#pragma unroll
            for (int d = 0; d < 4; ++d) {
                f32x2 hr2 = b2f2(hru[d]);
                int j0 = 2 * d;
                float bias0 = (j0 < 4) ? bb0[j0] : bb1[j0 - 4];
                float bias1 = (j0 + 1 < 4) ? bb0[j0 + 1] : bb1[j0 - 3];
                x[j0]     = fmaxf(sum[d][0] * inv + hr2[0] + bias0, 0.f);
                x[j0 + 1] = fmaxf(sum[d][1] * inv + hr2[1] + bias1, 0.f);
            }

            f32x4 up0 = *(const f32x4*)(P.up + f0), up1 = *(const f32x4*)(P.up + f0 + 4);
            f32x4 uq0 = *(const f32x4*)(P.uq + f0), uq1 = *(const f32x4*)(P.uq + f0 + 4);
            f32x4 vp0 = *(const f32x4*)(P.vp + f0), vp1 = *(const f32x4*)(P.vp + f0 + 4);
            f32x4 vq0 = *(const f32x4*)(P.vq + f0), vq1 = *(const f32x4*)(P.vq + f0 + 4);
            float ap = 0.f, aq = 0.f, tp = 0.f, tq = 0.f;
#pragma unroll
            for (int j = 0; j < 8; ++j) {
                float upj = (j < 4) ? up0[j] : up1[j - 4];
                float uqj = (j < 4) ? uq0[j] : uq1[j - 4];
                float vpj = (j < 4) ? vp0[j] : vp1[j - 4];
                float vqj = (j < 4) ? vq0[j] : vq1[j - 4];
                ap += x[j] * upj;
                aq += x[j] * uqj;
                tp += x[j] * vpj;
                tq += x[j] * vqj;
            }
#pragma unroll
            for (int m = 1; m <= 8; m <<= 1) {
                ap += __shfl_xor(ap, m, 64);
                aq += __shfl_xor(aq, m, 64);
                tp += __shfl_xor(tp, m, 64);
                tq += __shfl_xor(tq, m, 64);
            }
            if (l16 == 0) {
                P.S[node] = make_float2(ap, aq);
                P.T[node] = make_float2(tp, tq);
            }
        }
    }
    grid.sync();

    // ---------- phase 6: agg2 ----------
    {
        int wgid = bid * 4 + wave;
        float2 c = *P.cpq;
        for (int wi = wgid; wi < N_NODES / 16; wi += GRID * 4) {
            int slot = lane & 3;
            int node = wi * 16 + (lane >> 2);
            int beg = P.rowptr[node], end = P.rowptr[node + 1];
            float sp = 0.f, sq = 0.f;
            for (int e = beg + slot; e < end; e += 4) {
                float2 v = P.S[P.adj[e]];
                sp += v.x; sq += v.y;
            }
            sp += __shfl_xor(sp, 1, 64); sp += __shfl_xor(sp, 2, 64);
            sq += __shfl_xor(sq, 1, 64); sq += __shfl_xor(sq, 2, 64);
            if (slot == 0) {
                int deg = end - beg;
                float inv = deg > 0 ? 1.f / (float)deg : 0.f;
                float2 t = P.T[node];
                P.p[node] = sp * inv + t.x + c.x;
                P.q[node] = sq * inv + t.y + c.y;
            }
        }
    }
    grid.sync();

    // ---------- phase 7: link predictor ----------
    {
        float bl = P.blin[0];
        for (int i = gtid; i < N_LABELS; i += NTHREADS)
            P.out[i] = P.p[P.eli[i]] + P.q[P.eli[N_LABELS + i]] + bl;
    }
}

// ================= fallback: proven R6 multi-kernel path =================

__global__ void prep_k(const float* __restrict__ W1l, const float* __restrict__ W1r,
                       short* __restrict__ BT1,
                       const float* __restrict__ W2l, const float* __restrict__ W2r,
                       const float* __restrict__ Wlin, const float* __restrict__ b2,
                       float* __restrict__ up, float* __restrict__ uq,
                       float* __restrict__ vp, float* __restrict__ vq,
                       float2* __restrict__ cpq, int* __restrict__ cnt) {
    int b = blockIdx.x;
    int t = threadIdx.x;
    if (b < 128) {
        int i = b * 256 + t;
        int n = i >> 7, k = i & 127;
        float v = (n < 128) ? W1l[k * 128 + n] : W1r[k * 128 + (n - 128)];
        BT1[n * 128 + k] = f2b(v);
    } else if (b == 128) {
        const float* W = (t < 128) ? W2l : W2r;
        int k = t & 127;
        float s0 = 0.f, s1 = 0.f;
        for (int n = 0; n < 128; ++n) {
            float w = W[k * 128 + n];
            s0 += w * Wlin[n];
            s1 += w * Wlin[128 + n];
        }
        if (t < 128) { up[k] = s0; uq[k] = s1; }
        else         { vp[k] = s0; vq[k] = s1; }
    } else if (b == 129) {
        if (t < 64) {
            float p0 = b2[t] * Wlin[t] + b2[t + 64] * Wlin[t + 64];
            float q0 = b2[t] * Wlin[128 + t] + b2[t + 64] * Wlin[192 + t];
#pragma unroll
            for (int m = 1; m <= 32; m <<= 1) {
                p0 += __shfl_xor(p0, m, 64);
                q0 += __shfl_xor(q0, m, 64);
            }
            if (t == 0) *cpq = make_float2(p0, q0);
        }
    } else {
        int i = (b - 130) * 256 + t;
        if (i < N_NODES) cnt[i] = 0;
    }
}

__global__ void count_k(const int* __restrict__ ei, int* __restrict__ cnt) {
    int e = blockIdx.x * blockDim.x + threadIdx.x;
    if (e < N_EDGES) atomicAdd(&cnt[ei[N_EDGES + e]], 1);
}

__global__ void scan1_k(const int* __restrict__ cnt, int* __restrict__ rowptr,
                        int* __restrict__ partials) {
    __shared__ int s[256];
    int t = threadIdx.x;
    int i = blockIdx.x * 256 + t;
    int v = (i < N_NODES) ? cnt[i] : 0;
    s[t] = v;
    __syncthreads();
    for (int off = 1; off < 256; off <<= 1) {
        int x = s[t];
        int y = (t >= off) ? s[t - off] : 0;
        __syncthreads();
        s[t] = x + y;
        __syncthreads();
    }
    if (i < N_NODES) rowptr[i] = s[t] - v;
    if (t == 255) partials[blockIdx.x] = s[255];
}

__global__ void scanB_k(const int* __restrict__ partials, int* __restrict__ rowptr,
                        int* __restrict__ widx) {
    __shared__ int s[512];
    __shared__ int base_s;
    int t = threadIdx.x;
    int v = (t < NPARTS) ? partials[t] : 0;
    s[t] = v;
    __syncthreads();
    for (int off = 1; off < 512; off <<= 1) {
        int x = s[t];
        int y = (t >= off) ? s[t - off] : 0;
        __syncthreads();
        s[t] = x + y;
        __syncthreads();
    }
    int b = blockIdx.x;
    if (t == 0) base_s = (b > 0) ? s[b - 1] : 0;
    if (b == 0 && t == 0) rowptr[N_NODES] = s[NPARTS - 1];
    __syncthreads();
    if (t < 256) {
        int i = b * 256 + t;
        if (i < N_NODES) {
            int r = rowptr[i] + base_s;
            rowptr[i] = r;
            widx[i] = r;
        }
    }
}

__global__ void fill_k(const int* __restrict__ ei, int* __restrict__ widx,
                       int* __restrict__ adj) {
    int e = blockIdx.x * blockDim.x + threadIdx.x;
    if (e < N_EDGES) {
        int d = ei[N_EDGES + e];
        int pos = atomicAdd(&widx[d], 1);
        adj[pos] = ei[e];
    }
}

__global__ __launch_bounds__(256, 2) void gemm_k(const float* __restrict__ Af,
                                                 const short* __restrict__ BT,
                                                 short* __restrict__ Hl,
                                                 short* __restrict__ Hr) {
    int lane = threadIdx.x & 63;
    int wave = threadIdx.x >> 6;
    int quad = lane >> 4;
    int l16  = lane & 15;
    int half = wave & 1;
    int pair = blockIdx.x * 2 + (wave >> 1);
    const int P = GEMM_GRID * 2;

    short* __restrict__ H = half ? Hr : Hl;

    short8 Wf[8][4];
#pragma unroll
    for (int t = 0; t < 8; ++t)
#pragma unroll
        for (int kk = 0; kk < 4; ++kk)
            Wf[t][kk] = *(const short8*)(BT + (half * 128 + t * 16 + l16) * DIM + kk * 32 + quad * 8);

    for (int s = pair; s < NT_TILES; s += P) {
        long arow = (long)s * 16 + l16;
        short8 xf[4];
#pragma unroll
        for (int kk = 0; kk < 4; ++kk) {
            f32x4 a0 = *(const f32x4*)(Af + arow * DIM + kk * 32 + quad * 8);
            f32x4 a1 = *(const f32x4*)(Af + arow * DIM + kk * 32 + quad * 8 + 4);
            unsigned* xu = (unsigned*)&xf[kk];
            xu[0] = f2b2u(a0[0], a0[1]);
            xu[1] = f2b2u(a0[2], a0[3]);
            xu[2] = f2b2u(a1[0], a1[1]);
            xu[3] = f2b2u(a1[2], a1[3]);
        }
        f32x4 acc[8];
#pragma unroll
        for (int t = 0; t < 8; ++t)
#pragma unroll
            for (int r = 0; r < 4; ++r) acc[t][r] = 0.f;
#pragma unroll
        for (int kk = 0; kk < 4; ++kk)
#pragma unroll
            for (int t = 0; t < 8; ++t)
                acc[t] = __builtin_amdgcn_mfma_f32_16x16x32_bf16(Wf[t][kk], xf[kk], acc[t], 0, 0, 0);
#pragma unroll
        for (int t = 0; t < 8; ++t) {
            u32x2 o;
            o[0] = f2b2u(acc[t][0], acc[t][1]);
            o[1] = f2b2u(acc[t][2], acc[t][3]);
            *(u32x2*)(H + arow * DIM + t * 16 + quad * 4) = o;
        }
    }
}

__device__ __forceinline__ void gather_mean(const short* __restrict__ Hl,
                                            const int* __restrict__ rowptr,
                                            const int* __restrict__ adj,
                                            int node, int lane, f32x2 sum[4], float& inv) {
    int g  = lane >> 4;
    int f0 = (lane & 15) << 3;
    int beg = rowptr[node];
    int deg = rowptr[node + 1] - beg;
#pragma unroll
    for (int d = 0; d < 4; ++d) { sum[d][0] = 0.f; sum[d][1] = 0.f; }

    int av = (lane < deg) ? adj[beg + lane] : 0;
    int degc = deg < 64 ? deg : 64;

    u32x4 h0;
    bool v0 = false;
    if (degc > 0) {
        int idx = __shfl(av, g, 64);
        v0 = g < degc;
        if (v0) h0 = *(const u32x4*)(Hl + (long)idx * DIM + f0);
    }
    for (int e0 = 4; e0 < degc; e0 += 4) {
        int idx = __shfl(av, e0 + g, 64);
        bool v1 = (e0 + g) < degc;
        u32x4 h1;
        if (v1) h1 = *(const u32x4*)(Hl + (long)idx * DIM + f0);
        if (v0) {
#pragma unroll
            for (int d = 0; d < 4; ++d) sum[d] += b2f2(h0[d]);
        }
        h0 = h1; v0 = v1;
    }
    if (v0) {
#pragma unroll
        for (int d = 0; d < 4; ++d) sum[d] += b2f2(h0[d]);
    }
    for (int e0 = 64; e0 < deg; e0 += 4) {
        int e = e0 + g;
        if (e < deg) {
            int idx = adj[beg + e];
            u32x4 h = *(const u32x4*)(Hl + (long)idx * DIM + f0);
#pragma unroll
            for (int d = 0; d < 4; ++d) sum[d] += b2f2(h[d]);
        }
    }
#pragma unroll
    for (int d = 0; d < 4; ++d)
#pragma unroll
        for (int c = 0; c < 2; ++c) {
            sum[d][c] += __shfl_xor(sum[d][c], 16, 64);
            sum[d][c] += __shfl_xor(sum[d][c], 32, 64);
        }
    inv = deg > 0 ? 1.f / (float)deg : 0.f;
}

__global__ void agg1_k(const short* __restrict__ Hl, const short* __restrict__ Hr,
                       const int* __restrict__ rowptr, const int* __restrict__ adj,
                       const float* __restrict__ b1,
                       const float* __restrict__ up, const float* __restrict__ uq,
                       const float* __restrict__ vp, const float* __restrict__ vq,
                       float2* __restrict__ S, float2* __restrict__ T) {
    int lane = threadIdx.x & 63;
    int node = blockIdx.x * 4 + (threadIdx.x >> 6);
    int f0 = (lane & 15) << 3;
    if (node >= N_NODES) return;

    f32x2 sum[4]; float inv;
    gather_mean(Hl, rowptr, adj, node, lane, sum, inv);

    f32x4 bb0 = *(const f32x4*)(b1 + f0);
    f32x4 bb1 = *(const f32x4*)(b1 + f0 + 4);
    u32x4 hru = *(const u32x4*)(Hr + (long)node * DIM + f0);
    float x[8];
#pragma unroll
    for (int d = 0; d < 4; ++d) {
        f32x2 hr2 = b2f2(hru[d]);
        int j0 = 2 * d;
        float bias0 = (j0 < 4) ? bb0[j0] : bb1[j0 - 4];
        float bias1 = (j0 + 1 < 4) ? bb0[j0 + 1] : bb1[j0 - 3];
        x[j0]     = fmaxf(sum[d][0] * inv + hr2[0] + bias0, 0.f);
        x[j0 + 1] = fmaxf(sum[d][1] * inv + hr2[1] + bias1, 0.f);
    }

    f32x4 up0 = *(const f32x4*)(up + f0), up1 = *(const f32x4*)(up + f0 + 4);
    f32x4 uq0 = *(const f32x4*)(uq + f0), uq1 = *(const f32x4*)(uq + f0 + 4);
    f32x4 vp0 = *(const f32x4*)(vp + f0), vp1 = *(const f32x4*)(vp + f0 + 4);
    f32x4 vq0 = *(const f32x4*)(vq + f0), vq1 = *(const f32x4*)(vq + f0 + 4);
    float ap = 0.f, aq = 0.f, tp = 0.f, tq = 0.f;
#pragma unroll
    for (int j = 0; j < 8; ++j) {
        float upj = (j < 4) ? up0[j] : up1[j - 4];
        float uqj = (j < 4) ? uq0[j] : uq1[j - 4];
        float vpj = (j < 4) ? vp0[j] : vp1[j - 4];
        float vqj = (j < 4) ? vq0[j] : vq1[j - 4];
        ap += x[j] * upj;
        aq += x[j] * uqj;
        tp += x[j] * vpj;
        tq += x[j] * vqj;
    }
#pragma unroll
    for (int m = 1; m <= 8; m <<= 1) {
        ap += __shfl_xor(ap, m, 64);
        aq += __shfl_xor(aq, m, 64);
        tp += __shfl_xor(tp, m, 64);
        tq += __shfl_xor(tq, m, 64);
    }
    if (lane == 0) {
        S[node] = make_float2(ap, aq);
        T[node] = make_float2(tp, tq);
    }
}

__global__ void agg2_k(const int* __restrict__ rowptr, const int* __restrict__ adj,
                       const float2* __restrict__ S, const float2* __restrict__ T,
                       const float2* __restrict__ cpq,
                       float* __restrict__ p, float* __restrict__ q) {
    int lane = threadIdx.x & 63;
    int wavei = blockIdx.x * 4 + (threadIdx.x >> 6);
    int slot = lane & 3;
    int node = wavei * 16 + (lane >> 2);
    if (node >= N_NODES) return;
    int beg = rowptr[node], end = rowptr[node + 1];
    float sp = 0.f, sq = 0.f;
    for (int e = beg + slot; e < end; e += 4) {
        float2 v = S[adj[e]];
        sp += v.x; sq += v.y;
    }
    sp += __shfl_xor(sp, 1, 64); sp += __shfl_xor(sp, 2, 64);
    sq += __shfl_xor(sq, 1, 64); sq += __shfl_xor(sq, 2, 64);
    if (slot == 0) {
        int deg = end - beg;
        float inv = deg > 0 ? 1.f / (float)deg : 0.f;
        float2 t = T[node];
        float2 c = *cpq;
        p[node] = sp * inv + t.x + c.x;
        q[node] = sq * inv + t.y + c.y;
    }
}

__global__ void out_k(const int* __restrict__ eli, const float* __restrict__ p,
                      const float* __restrict__ q, const float* __restrict__ blin,
                      float* __restrict__ out) {
    int i = blockIdx.x * blockDim.x + threadIdx.x;
    if (i < N_LABELS) out[i] = p[eli[i]] + q[eli[N_LABELS + i]] + blin[0];
}

// ---------------- launch ----------------

extern "C" void kernel_launch(void* const* d_in, const int* in_sizes, int n_in,
                              void* d_out, int out_size, void* d_ws, size_t ws_size,
                              hipStream_t stream) {
    Params P;
    P.ei   = (const int*)d_in[0];
    P.eli  = (const int*)d_in[1];
    P.emb  = (const float*)d_in[2];
    P.W1l  = (const float*)d_in[3];
    P.b1   = (const float*)d_in[4];
    P.W1r  = (const float*)d_in[5];
    P.W2l  = (const float*)d_in[6];
    P.b2   = (const float*)d_in[7];
    P.W2r  = (const float*)d_in[8];
    P.Wlin = (const float*)d_in[9];
    P.blin = (const float*)d_in[10];
    P.out  = (float*)d_out;

    char* ws = (char*)d_ws;
    size_t off = 0;
    auto alloc = [&](size_t bytes) -> void* {
        off = (off + 255) & ~(size_t)255;
        void* ptr = ws + off;
        off += bytes;
        return ptr;
    };

    P.Hl  = (short*)alloc((size_t)N_NODES * DIM * 2);
    P.Hr  = (short*)alloc((size_t)N_NODES * DIM * 2);
    P.BT1 = (short*)alloc(256 * 128 * 2);
    P.up = (float*)alloc(128 * 4);
    P.uq = (float*)alloc(128 * 4);
    P.vp = (float*)alloc(128 * 4);
    P.vq = (float*)alloc(128 * 4);
    P.cpq = (float2*)alloc(8);
    P.cnt      = (int*)alloc((size_t)N_NODES * 4);
    P.rowptr   = (int*)alloc((size_t)(N_NODES + 1) * 4);
    P.widx     = (int*)alloc((size_t)N_NODES * 4);
    P.adj      = (int*)alloc((size_t)N_EDGES * 4);
    P.partials = (int*)alloc(NPARTS * 4);
    P.S        = (float2*)alloc((size_t)N_NODES * 8);
    P.T        = (float2*)alloc((size_t)N_NODES * 8);
    P.p        = (float*)alloc((size_t)N_NODES * 4);
    P.q        = (float*)alloc((size_t)N_NODES * 4);

    void* args[] = { (void*)&P };
    hipError_t err = hipLaunchCooperativeKernel((const void*)mega_k, dim3(GRID), dim3(256),
                                                args, 0, stream);
    if (err != hipSuccess) {
        // fallback: proven multi-kernel sequence (identical math)
        prep_k<<<130 + NPARTS, 256, 0, stream>>>(P.W1l, P.W1r, P.BT1, P.W2l, P.W2r, P.Wlin, P.b2,
                                                 P.up, P.uq, P.vp, P.vq, P.cpq, P.cnt);
        count_k<<<(N_EDGES + 255) / 256, 256, 0, stream>>>(P.ei, P.cnt);
        scan1_k<<<NPARTS, 256, 0, stream>>>(P.cnt, P.rowptr, P.partials);
        scanB_k<<<NPARTS, 512, 0, stream>>>(P.partials, P.rowptr, P.widx);
        fill_k<<<(N_EDGES + 255) / 256, 256, 0, stream>>>(P.ei, P.widx, P.adj);
        gemm_k<<<GEMM_GRID, 256, 0, stream>>>(P.emb, P.BT1, P.Hl, P.Hr);
        agg1_k<<<N_NODES / 4, 256, 0, stream>>>(P.Hl, P.Hr, P.rowptr, P.adj, P.b1,
                                                P.up, P.uq, P.vp, P.vq, P.S, P.T);
        agg2_k<<<(N_NODES + 63) / 64, 256, 0, stream>>>(P.rowptr, P.adj, P.S, P.T, P.cpq, P.p, P.q);
        out_k<<<(N_LABELS + 255) / 256, 256, 0, stream>>>(P.eli, P.p, P.q, P.blin, P.out);
    }
}